// Round 3
// baseline (1150.862 us; speedup 1.0000x reference)
//
#include <hip/hip_runtime.h>
#include <math.h>

#define DG 256
#define DL 10
#define CHUNK 128

__device__ __forceinline__ float leaky(float x) { return x > 0.f ? x : 0.01f * x; }
__device__ __forceinline__ float sigmoidf(float x) { return 1.f / (1.f + expf(-x)); }

// starts[b] = first node index with seg >= b (segments sorted); starts[B] = N.
// segment_ids is int64 in the reference; harness may pass int64 raw or int32.
// Detect: word N-1 is the HIGH word of the last int64 element (== 0) for int64
// layout; for int32 layout it's the last segment id (nonzero w.p. ~1).
__global__ void k_starts(const int* __restrict__ seg, int* __restrict__ starts, int N, int B) {
  const int stride = (seg[N - 1] == 0) ? 2 : 1;  // 2 => int64 little-endian low words
  int b = blockIdx.x * blockDim.x + threadIdx.x;
  if (b > B) return;
  if (b == B) { starts[B] = N; return; }
  int lo = 0, hi = N;
  while (lo < hi) {
    int mid = (lo + hi) >> 1;
    if (seg[(size_t)mid * stride] < b) lo = mid + 1; else hi = mid;
  }
  starts[b] = lo;
}

// glog[b][j] = relu(gf[b]) . W_l1[j, 0:256] + b_l1[j]   (graph part of logit MLP, hoisted)
__global__ void k_glog(const float* __restrict__ gf, const float* __restrict__ W_l1,
                       const float* __restrict__ b_l1, float* __restrict__ glog) {
  int b = blockIdx.x;
  int l = threadIdx.x; // 64 lanes
  float4 g4 = *(const float4*)(gf + (size_t)b * DG + 4 * l);
  g4.x = fmaxf(g4.x, 0.f); g4.y = fmaxf(g4.y, 0.f);
  g4.z = fmaxf(g4.z, 0.f); g4.w = fmaxf(g4.w, 0.f);
  float p[DL];
#pragma unroll
  for (int j = 0; j < DL; ++j) {
    float4 w4 = *(const float4*)(W_l1 + (size_t)j * 512 + 4 * l);
    p[j] = g4.x * w4.x + g4.y * w4.y + g4.z * w4.z + g4.w * w4.w;
  }
#pragma unroll
  for (int m = 32; m >= 1; m >>= 1) {
#pragma unroll
    for (int j = 0; j < DL; ++j) p[j] += __shfl_xor(p[j], m);
  }
  if (l == 0) {
#pragma unroll
    for (int j = 0; j < DL; ++j) glog[b * DL + j] = p[j] + b_l1[j];
  }
}

// out[c*R + r] = in[r*C + c]
__global__ void k_transpose(const float* __restrict__ in, float* __restrict__ out, int R, int C) {
  int idx = blockIdx.x * blockDim.x + threadIdx.x;
  if (idx >= R * C) return;
  int r = idx / C, c = idx - r * C;
  out[c * R + r] = in[idx];
}

// One block (256 threads) per graph. Online softmax over chunks of CHUNK nodes.
// pooled[b][t] = sum_i alpha_i * node[i][t]
__global__ __launch_bounds__(256) void k_pool(
    const float* __restrict__ nf, const int* __restrict__ starts,
    const float* __restrict__ glog, const float* __restrict__ W_l1,
    const float* __restrict__ W_l2, const float* __restrict__ b_l2_p,
    float* __restrict__ pooled) {
  __shared__ float slog[CHUNK];
  __shared__ float sex[CHUNK];

  const int b = blockIdx.x;
  const int tid = threadIdx.x;
  const int lane = tid & 63;
  const int wave = tid >> 6;

  const int start = starts[b];
  const int end   = starts[b + 1];

  // W_l1 node part for this lane's 4 dims (d = 4*lane + c), held in VGPRs
  float wl[DL][4];
#pragma unroll
  for (int j = 0; j < DL; ++j) {
    float4 w4 = *(const float4*)(W_l1 + (size_t)j * 512 + 256 + 4 * lane);
    wl[j][0] = w4.x; wl[j][1] = w4.y; wl[j][2] = w4.z; wl[j][3] = w4.w;
  }
  float gl[DL];
#pragma unroll
  for (int j = 0; j < DL; ++j) gl[j] = glog[b * DL + j];
  float wl2[DL];
#pragma unroll
  for (int j = 0; j < DL; ++j) wl2[j] = W_l2[j];
  const float bl2 = b_l2_p[0];

  float M = -INFINITY;
  float denom = 0.f;
  float pool = 0.f;  // this thread's dim = tid

  for (int c0 = start; c0 < end; c0 += CHUNK) {
    const int cn = min(CHUNK, end - c0);

    // ---- phase 1: logits, one wave per node ----
    for (int n = wave; n < cn; n += 4) {
      const float4 x4 = *(const float4*)(nf + ((size_t)(c0 + n) << 8) + 4 * lane);
      float p[DL];
#pragma unroll
      for (int j = 0; j < DL; ++j)
        p[j] = x4.x * wl[j][0] + x4.y * wl[j][1] + x4.z * wl[j][2] + x4.w * wl[j][3];
#pragma unroll
      for (int m = 32; m >= 1; m >>= 1) {
#pragma unroll
        for (int j = 0; j < DL; ++j) p[j] += __shfl_xor(p[j], m);
      }
      float lg = bl2;
#pragma unroll
      for (int j = 0; j < DL; ++j) {
        float h = leaky(p[j] + gl[j]);
        lg += h * wl2[j];
      }
      lg = leaky(lg);
      if (lane == 0) slog[n] = lg;
    }
    __syncthreads();

    // ---- online softmax update (redundant per thread, all identical) ----
    float mc = -INFINITY;
    for (int n = 0; n < cn; ++n) mc = fmaxf(mc, slog[n]);
    const float Mn = fmaxf(M, mc);
    const float sc = expf(M - Mn);  // M=-inf -> 0
    pool *= sc;
    denom *= sc;
    M = Mn;
    if (tid < cn) sex[tid] = expf(slog[tid] - Mn);
    __syncthreads();

    float dsum = 0.f;
    for (int n = 0; n < cn; ++n) dsum += sex[n];
    denom += dsum;

    // ---- phase 2: weighted accumulate; thread t owns dim t ----
    const float* rowp = nf + ((size_t)c0 << 8) + tid;
#pragma unroll 4
    for (int n = 0; n < cn; ++n) {
      pool += sex[n] * rowp[(size_t)n << 8];
    }
    __syncthreads();
  }

  pooled[(size_t)b * 256 + tid] = pool / fmaxf(denom, 1e-30f);
}

// GRU + output. 8 graphs per block, 256 threads.
// thread t: dims 4*dt..4*dt+3 (dt = t&63), graphs g0+{0,1} (g0 = 2*(t>>6))
__global__ __launch_bounds__(256) void k_gru(
    const float* __restrict__ pooled, const float* __restrict__ gf,
    const float* __restrict__ WmsgT, const float* __restrict__ b_msg,
    const float* __restrict__ WihT, const float* __restrict__ WhhT,
    const float* __restrict__ b_ih, const float* __restrict__ b_hh,
    float* __restrict__ out) {
  __shared__ float pool_s[8][256];
  __shared__ float gf_s[8][256];
  __shared__ float ctx_s[8][256];

  const int t = threadIdx.x;
  const int b0 = blockIdx.x * 8;
  const int dt = t & 63;
  const int g0 = (t >> 6) * 2;

  // stage pooled + graph_feats
#pragma unroll
  for (int g = 0; g < 8; ++g) {
    pool_s[g][t] = pooled[(size_t)(b0 + g) * 256 + t];
    gf_s[g][t]   = gf[(size_t)(b0 + g) * 256 + t];
  }
  __syncthreads();

  // ---- context = pooled @ W_msg.T + b_msg ----
  {
    float acc[2][4] = {{0.f,0.f,0.f,0.f},{0.f,0.f,0.f,0.f}};
#pragma unroll 4
    for (int k = 0; k < 256; ++k) {
      float4 w = *(const float4*)(WmsgT + (size_t)k * 256 + 4 * dt);
#pragma unroll
      for (int gi = 0; gi < 2; ++gi) {
        float p = pool_s[g0 + gi][k];
        acc[gi][0] += p * w.x; acc[gi][1] += p * w.y;
        acc[gi][2] += p * w.z; acc[gi][3] += p * w.w;
      }
    }
    float4 bm = *(const float4*)(b_msg + 4 * dt);
#pragma unroll
    for (int gi = 0; gi < 2; ++gi) {
      ctx_s[g0 + gi][4 * dt + 0] = acc[gi][0] + bm.x;
      ctx_s[g0 + gi][4 * dt + 1] = acc[gi][1] + bm.y;
      ctx_s[g0 + gi][4 * dt + 2] = acc[gi][2] + bm.z;
      ctx_s[g0 + gi][4 * dt + 3] = acc[gi][3] + bm.w;
    }
  }
  __syncthreads();

  float r[2][4], z[2][4];

  // ---- section 0: r, section 1: z ----
#pragma unroll
  for (int s = 0; s < 2; ++s) {
    float ai[2][4] = {{0.f,0.f,0.f,0.f},{0.f,0.f,0.f,0.f}};
    float ah[2][4] = {{0.f,0.f,0.f,0.f},{0.f,0.f,0.f,0.f}};
#pragma unroll 4
    for (int k = 0; k < 256; ++k) {
      float4 wi = *(const float4*)(WihT + (size_t)k * 768 + s * 256 + 4 * dt);
      float4 wh = *(const float4*)(WhhT + (size_t)k * 768 + s * 256 + 4 * dt);
#pragma unroll
      for (int gi = 0; gi < 2; ++gi) {
        float c = ctx_s[g0 + gi][k];
        float h = gf_s[g0 + gi][k];
        ai[gi][0] += c * wi.x; ai[gi][1] += c * wi.y; ai[gi][2] += c * wi.z; ai[gi][3] += c * wi.w;
        ah[gi][0] += h * wh.x; ah[gi][1] += h * wh.y; ah[gi][2] += h * wh.z; ah[gi][3] += h * wh.w;
      }
    }
    float4 bi = *(const float4*)(b_ih + s * 256 + 4 * dt);
    float4 bh = *(const float4*)(b_hh + s * 256 + 4 * dt);
#pragma unroll
    for (int gi = 0; gi < 2; ++gi) {
      float v0 = sigmoidf(ai[gi][0] + bi.x + ah[gi][0] + bh.x);
      float v1 = sigmoidf(ai[gi][1] + bi.y + ah[gi][1] + bh.y);
      float v2 = sigmoidf(ai[gi][2] + bi.z + ah[gi][2] + bh.z);
      float v3 = sigmoidf(ai[gi][3] + bi.w + ah[gi][3] + bh.w);
      if (s == 0) { r[gi][0]=v0; r[gi][1]=v1; r[gi][2]=v2; r[gi][3]=v3; }
      else        { z[gi][0]=v0; z[gi][1]=v1; z[gi][2]=v2; z[gi][3]=v3; }
    }
  }

  // ---- section 2: n and output ----
  {
    float ai[2][4] = {{0.f,0.f,0.f,0.f},{0.f,0.f,0.f,0.f}};
    float ah[2][4] = {{0.f,0.f,0.f,0.f},{0.f,0.f,0.f,0.f}};
#pragma unroll 4
    for (int k = 0; k < 256; ++k) {
      float4 wi = *(const float4*)(WihT + (size_t)k * 768 + 512 + 4 * dt);
      float4 wh = *(const float4*)(WhhT + (size_t)k * 768 + 512 + 4 * dt);
#pragma unroll
      for (int gi = 0; gi < 2; ++gi) {
        float c = ctx_s[g0 + gi][k];
        float h = gf_s[g0 + gi][k];
        ai[gi][0] += c * wi.x; ai[gi][1] += c * wi.y; ai[gi][2] += c * wi.z; ai[gi][3] += c * wi.w;
        ah[gi][0] += h * wh.x; ah[gi][1] += h * wh.y; ah[gi][2] += h * wh.z; ah[gi][3] += h * wh.w;
      }
    }
    float4 bi = *(const float4*)(b_ih + 512 + 4 * dt);
    float4 bh = *(const float4*)(b_hh + 512 + 4 * dt);
#pragma unroll
    for (int gi = 0; gi < 2; ++gi) {
      float4 o;
      float hf0 = gf_s[g0 + gi][4 * dt + 0];
      float hf1 = gf_s[g0 + gi][4 * dt + 1];
      float hf2 = gf_s[g0 + gi][4 * dt + 2];
      float hf3 = gf_s[g0 + gi][4 * dt + 3];
      float n0 = tanhf(ai[gi][0] + bi.x + r[gi][0] * (ah[gi][0] + bh.x));
      float n1 = tanhf(ai[gi][1] + bi.y + r[gi][1] * (ah[gi][1] + bh.y));
      float n2 = tanhf(ai[gi][2] + bi.z + r[gi][2] * (ah[gi][2] + bh.z));
      float n3 = tanhf(ai[gi][3] + bi.w + r[gi][3] * (ah[gi][3] + bh.w));
      o.x = (1.f - z[gi][0]) * n0 + z[gi][0] * hf0;
      o.y = (1.f - z[gi][1]) * n1 + z[gi][1] * hf1;
      o.z = (1.f - z[gi][2]) * n2 + z[gi][2] * hf2;
      o.w = (1.f - z[gi][3]) * n3 + z[gi][3] * hf3;
      // BUGFIX R2: was (b0 + gi) — dropped g0, so waves 1-3 raced onto
      // graphs b0/b0+1 and graphs b0+2..b0+7 were never written.
      *(float4*)(out + (size_t)(b0 + g0 + gi) * 256 + 4 * dt) = o;
    }
  }
}

extern "C" void kernel_launch(void* const* d_in, const int* in_sizes, int n_in,
                              void* d_out, int out_size, void* d_ws, size_t ws_size,
                              hipStream_t stream) {
  const float* nf    = (const float*)d_in[0];
  const float* gf    = (const float*)d_in[1];
  const int*   seg   = (const int*)d_in[2];
  const float* W_msg = (const float*)d_in[3];
  const float* b_msg = (const float*)d_in[4];
  const float* W_l1  = (const float*)d_in[5];
  const float* b_l1  = (const float*)d_in[6];
  const float* W_l2  = (const float*)d_in[7];
  const float* b_l2  = (const float*)d_in[8];
  const float* W_ih  = (const float*)d_in[9];
  const float* W_hh  = (const float*)d_in[10];
  const float* b_ih  = (const float*)d_in[11];
  const float* b_hh  = (const float*)d_in[12];
  float* out = (float*)d_out;

  const int N = in_sizes[0] / 256;
  const int B = in_sizes[1] / 256;

  size_t off = 0;
  char* base = (char*)d_ws;
  auto alloc = [&](size_t bytes) -> void* {
    void* p = base + off;
    off += (bytes + 255) & ~(size_t)255;
    return p;
  };
  int*   starts = (int*)  alloc((size_t)(B + 1) * sizeof(int));
  float* glog   = (float*)alloc((size_t)B * DL * sizeof(float));
  float* WmsgT  = (float*)alloc((size_t)256 * 256 * sizeof(float));
  float* WihT   = (float*)alloc((size_t)768 * 256 * sizeof(float));
  float* WhhT   = (float*)alloc((size_t)768 * 256 * sizeof(float));
  float* pooled = (float*)alloc((size_t)B * 256 * sizeof(float));

  k_starts<<<(B + 1 + 255) / 256, 256, 0, stream>>>(seg, starts, N, B);
  k_glog<<<B, 64, 0, stream>>>(gf, W_l1, b_l1, glog);
  k_transpose<<<(256 * 256 + 255) / 256, 256, 0, stream>>>(W_msg, WmsgT, 256, 256);
  k_transpose<<<(768 * 256 + 255) / 256, 256, 0, stream>>>(W_ih, WihT, 768, 256);
  k_transpose<<<(768 * 256 + 255) / 256, 256, 0, stream>>>(W_hh, WhhT, 768, 256);
  k_pool<<<B, 256, 0, stream>>>(nf, starts, glog, W_l1, W_l2, b_l2, pooled);
  k_gru<<<B / 8, 256, 0, stream>>>(pooled, gf, WmsgT, b_msg, WihT, WhhT, b_ih, b_hh, out);
}